// Round 7
// baseline (117.982 us; speedup 1.0000x reference)
//
#include <hip/hip_runtime.h>
#include <math.h>

#define NN 8192
#define NEMBD 128
#define NHID 64
#define NCLS 16
#define MAXN 256
#define NEG_SLOPE 0.2f
#define WPB 4   // waves per block
#define RPW 4   // rows per wave

typedef float f4 __attribute__((ext_vector_type(4)));

__device__ __forceinline__ float wave_max64(float v) {
    v = fmaxf(v, __shfl_xor(v, 1));
    v = fmaxf(v, __shfl_xor(v, 2));
    v = fmaxf(v, __shfl_xor(v, 4));
    v = fmaxf(v, __shfl_xor(v, 8));
    v = fmaxf(v, __shfl_xor(v, 16));
    v = fmaxf(v, __shfl_xor(v, 32));
    return v;
}
__device__ __forceinline__ float wave_sum64(float v) {
    v += __shfl_xor(v, 1);
    v += __shfl_xor(v, 2);
    v += __shfl_xor(v, 4);
    v += __shfl_xor(v, 8);
    v += __shfl_xor(v, 16);
    v += __shfl_xor(v, 32);
    return v;
}

// K_A: h1 = x @ W1 (+ layer-1 alphas). wave per row, lane = hidden feature.
__global__ __launch_bounds__(256) void kA_h1(
    const float* __restrict__ x, const float* __restrict__ W1,
    const float* __restrict__ a1s, const float* __restrict__ a1d,
    float* __restrict__ h1, float* __restrict__ als, float* __restrict__ ald) {
    int wid = threadIdx.x >> 6, lane = threadIdx.x & 63;
    int row = blockIdx.x * 4 + wid;
    const float* xr = x + (size_t)row * NEMBD;
    float acc = 0.f;
#pragma unroll 8
    for (int k = 0; k < NEMBD; ++k)
        acc = fmaf(xr[k], W1[k * NHID + lane], acc);
    h1[(size_t)row * NHID + lane] = acc;
    float ts = wave_sum64(acc * a1s[lane]);
    float td = wave_sum64(acc * a1d[lane]);
    if (lane == 0) { als[row] = ts; ald[row] = td; }
}

// K_B: per wave, 4 rows pipelined: scan row r (adj stream, ballot compaction)
// while gathering row r-1's attention output slice-by-slice. Per chunk the
// gather loads issue BEFORE the scan prefetch so vmcnt in-order retirement
// never makes gather-consumption wait on young HBM loads. Softmax after each
// scan; per-row finalize computes ELU + h2 (@W2) + layer-2 alphas inline.
__global__ __launch_bounds__(256) void kB_fused(
    const float* __restrict__ adj, const float* __restrict__ h1,
    const float* __restrict__ als, const float* __restrict__ ald,
    const float* __restrict__ b1, const float* __restrict__ W2,
    const float* __restrict__ a2s, const float* __restrict__ a2d,
    int* __restrict__ g_cnt, int* __restrict__ g_nbr,
    float* __restrict__ h2, float* __restrict__ als2, float* __restrict__ ald2) {
    __shared__ int   S_idx[WPB][2][MAXN];
    __shared__ float S_p[WPB][2][MAXN];
    __shared__ float S_h[WPB][NHID];
    int wid = threadIdx.x >> 6, lane = threadIdx.x & 63;
    int row0 = (blockIdx.x * WPB + wid) * RPW;
    unsigned long long lt = (1ull << lane) - 1ull;
    int c4 = lane & 15, kk = lane >> 4;

    int pcnt = 0, prow = -1;
    float prinv = 0.f;
    f4 acc = {0.f, 0.f, 0.f, 0.f};

#pragma unroll 1
    for (int r = 0; r < RPW; ++r) {
        int row = row0 + r;
        int buf = r & 1, pb = buf ^ 1;
        const f4* arow = (const f4*)(adj + (size_t)row * NN);
        int base = 0;
        f4 cur0 = __builtin_nontemporal_load(arow + 0 * 64 + lane);
        f4 cur1 = __builtin_nontemporal_load(arow + 1 * 64 + lane);
        f4 cur2 = __builtin_nontemporal_load(arow + 2 * 64 + lane);
        f4 cur3 = __builtin_nontemporal_load(arow + 3 * 64 + lane);

#pragma unroll 1
        for (int c = 0; c < 8; ++c) {
            // --- gather slice c of previous row (issued first: oldest loads)
            if (r > 0) {
                int lo = (pcnt * c) >> 3, hi = (pcnt * (c + 1)) >> 3;
#pragma unroll 2
                for (int n = lo + kk; n < hi; n += 4) {
                    float p = S_p[wid][pb][n];
                    int j = S_idx[wid][pb][n];
                    f4 v = ((const f4*)(h1 + (size_t)j * NHID))[c4];
                    acc.x = fmaf(p, v.x, acc.x);
                    acc.y = fmaf(p, v.y, acc.y);
                    acc.z = fmaf(p, v.z, acc.z);
                    acc.w = fmaf(p, v.w, acc.w);
                }
            }
            // --- prefetch next scan chunk (young loads, stay in flight)
            f4 n0 = {0,0,0,0}, n1 = {0,0,0,0}, n2 = {0,0,0,0}, n3 = {0,0,0,0};
            if (c < 7) {
                const f4* p = arow + (c + 1) * 256 + lane;
                n0 = __builtin_nontemporal_load(p + 0 * 64);
                n1 = __builtin_nontemporal_load(p + 1 * 64);
                n2 = __builtin_nontemporal_load(p + 2 * 64);
                n3 = __builtin_nontemporal_load(p + 3 * 64);
            }
            // --- ballots on current chunk (waits only oldest loads)
#pragma unroll
            for (int j = 0; j < 4; ++j) {
                f4 v = (j == 0) ? cur0 : (j == 1) ? cur1 : (j == 2) ? cur2 : cur3;
                int it = c * 4 + j;
#pragma unroll
                for (int s = 0; s < 4; ++s) {
                    bool nz = v[s] > 0.f;
                    unsigned long long m = __ballot(nz);
                    if (nz) {
                        int pos = base + __popcll(m & lt);
                        if (pos < MAXN) S_idx[wid][buf][pos] = it * 256 + lane * 4 + s;
                    }
                    base += __popcll(m);
                }
            }
            cur0 = n0; cur1 = n1; cur2 = n2; cur3 = n3;
        }

        int cnt = base < MAXN ? base : MAXN;
        if (lane == 0) g_cnt[row] = cnt;
        for (int n = lane; n < cnt; n += 64)
            g_nbr[(size_t)row * MAXN + n] = S_idx[wid][buf][n];

        // --- finalize previous row (its gather completed in the chunk loop)
        if (r > 0) {
            acc.x += __shfl_xor(acc.x, 16); acc.y += __shfl_xor(acc.y, 16);
            acc.z += __shfl_xor(acc.z, 16); acc.w += __shfl_xor(acc.w, 16);
            acc.x += __shfl_xor(acc.x, 32); acc.y += __shfl_xor(acc.y, 32);
            acc.z += __shfl_xor(acc.z, 32); acc.w += __shfl_xor(acc.w, 32);
            if (kk == 0) {
                f4 o;
#pragma unroll
                for (int j = 0; j < 4; ++j) {
                    float t = acc[j] * prinv + b1[c4 * 4 + j];
                    o[j] = t > 0.f ? t : expm1f(t);
                }
                ((f4*)S_h[wid])[c4] = o;
            }
            float a2 = 0.f;
#pragma unroll
            for (int f = kk * 16; f < kk * 16 + 16; ++f)
                a2 = fmaf(S_h[wid][f], W2[f * NCLS + c4], a2);
            a2 += __shfl_xor(a2, 16);
            a2 += __shfl_xor(a2, 32);
            if (lane < 16) h2[(size_t)prow * NCLS + lane] = a2;
            float ts = a2 * a2s[c4], td = a2 * a2d[c4];
            ts += __shfl_xor(ts, 1); td += __shfl_xor(td, 1);
            ts += __shfl_xor(ts, 2); td += __shfl_xor(td, 2);
            ts += __shfl_xor(ts, 4); td += __shfl_xor(td, 4);
            ts += __shfl_xor(ts, 8); td += __shfl_xor(td, 8);
            if (lane == 0) { als2[prow] = ts; ald2[prow] = td; }
            acc = (f4){0.f, 0.f, 0.f, 0.f};
        }

        // --- softmax of row r into S_p[buf]
        float asr = als[row];
        float mloc = -1e30f;
        for (int n = lane; n < cnt; n += 64) {
            float e = asr + ald[S_idx[wid][buf][n]];
            e = e > 0.f ? e : NEG_SLOPE * e;
            S_p[wid][buf][n] = e;
            mloc = fmaxf(mloc, e);
        }
        float mrow = wave_max64(mloc);
        float ssum = 0.f;
        for (int n = lane; n < cnt; n += 64) {
            float p = __expf(S_p[wid][buf][n] - mrow);
            S_p[wid][buf][n] = p;
            ssum += p;
        }
        prinv = 1.f / wave_sum64(ssum);
        pcnt = cnt; prow = row;
    }

    // --- final row's gather (exposed tail) + finalize
    {
        int pb = (RPW - 1) & 1;
#pragma unroll 2
        for (int n = kk; n < pcnt; n += 4) {
            float p = S_p[wid][pb][n];
            int j = S_idx[wid][pb][n];
            f4 v = ((const f4*)(h1 + (size_t)j * NHID))[c4];
            acc.x = fmaf(p, v.x, acc.x);
            acc.y = fmaf(p, v.y, acc.y);
            acc.z = fmaf(p, v.z, acc.z);
            acc.w = fmaf(p, v.w, acc.w);
        }
        acc.x += __shfl_xor(acc.x, 16); acc.y += __shfl_xor(acc.y, 16);
        acc.z += __shfl_xor(acc.z, 16); acc.w += __shfl_xor(acc.w, 16);
        acc.x += __shfl_xor(acc.x, 32); acc.y += __shfl_xor(acc.y, 32);
        acc.z += __shfl_xor(acc.z, 32); acc.w += __shfl_xor(acc.w, 32);
        if (kk == 0) {
            f4 o;
#pragma unroll
            for (int j = 0; j < 4; ++j) {
                float t = acc[j] * prinv + b1[c4 * 4 + j];
                o[j] = t > 0.f ? t : expm1f(t);
            }
            ((f4*)S_h[wid])[c4] = o;
        }
        float a2 = 0.f;
#pragma unroll
        for (int f = kk * 16; f < kk * 16 + 16; ++f)
            a2 = fmaf(S_h[wid][f], W2[f * NCLS + c4], a2);
        a2 += __shfl_xor(a2, 16);
        a2 += __shfl_xor(a2, 32);
        if (lane < 16) h2[(size_t)prow * NCLS + lane] = a2;
        float ts = a2 * a2s[c4], td = a2 * a2d[c4];
        ts += __shfl_xor(ts, 1); td += __shfl_xor(td, 1);
        ts += __shfl_xor(ts, 2); td += __shfl_xor(td, 2);
        ts += __shfl_xor(ts, 4); td += __shfl_xor(td, 4);
        ts += __shfl_xor(ts, 8); td += __shfl_xor(td, 8);
        if (lane == 0) { als2[prow] = ts; ald2[prow] = td; }
    }
}

// K3: layer-2 GAT from saved neighbor lists. lane = (c4 in 0..3, kk16 in 0..15).
__global__ __launch_bounds__(256) void k3_attn2(
    const float* __restrict__ h2, const float* __restrict__ als2,
    const float* __restrict__ ald2, const float* __restrict__ b2,
    const int* __restrict__ g_cnt, const int* __restrict__ g_nbr,
    float* __restrict__ out) {
    __shared__ int   s_idx[4][MAXN];
    __shared__ float s_p[4][MAXN];
    int wid = threadIdx.x >> 6, lane = threadIdx.x & 63;
    int row = blockIdx.x * 4 + wid;
    int cnt = g_cnt[row];
    for (int n = lane; n < cnt; n += 64) s_idx[wid][n] = g_nbr[(size_t)row * MAXN + n];

    float asrow = als2[row];
    float mloc = -1e30f;
    for (int n = lane; n < cnt; n += 64) {
        float e = asrow + ald2[s_idx[wid][n]];
        e = e > 0.f ? e : NEG_SLOPE * e;
        s_p[wid][n] = e;
        mloc = fmaxf(mloc, e);
    }
    float mrow = wave_max64(mloc);
    float ssum = 0.f;
    for (int n = lane; n < cnt; n += 64) {
        float p = __expf(s_p[wid][n] - mrow);
        s_p[wid][n] = p;
        ssum += p;
    }
    float rinv = 1.f / wave_sum64(ssum);

    int c4 = lane & 3, kk = lane >> 2;
    f4 acc = {0.f, 0.f, 0.f, 0.f};
#pragma unroll 2
    for (int n = kk; n < cnt; n += 16) {
        float p = s_p[wid][n];
        f4 v = ((const f4*)(h2 + (size_t)s_idx[wid][n] * NCLS))[c4];
        acc.x = fmaf(p, v.x, acc.x);
        acc.y = fmaf(p, v.y, acc.y);
        acc.z = fmaf(p, v.z, acc.z);
        acc.w = fmaf(p, v.w, acc.w);
    }
#pragma unroll
    for (int d = 4; d <= 32; d <<= 1) {
        acc.x += __shfl_xor(acc.x, d); acc.y += __shfl_xor(acc.y, d);
        acc.z += __shfl_xor(acc.z, d); acc.w += __shfl_xor(acc.w, d);
    }
    if (kk == 0) {
        f4 o;
#pragma unroll
        for (int j = 0; j < 4; ++j) {
            float t = acc[j] * rinv + b2[c4 * 4 + j];
            o[j] = t > 0.f ? t : expm1f(t);
        }
        ((f4*)(out + (size_t)row * NCLS))[c4] = o;
    }
}

extern "C" void kernel_launch(void* const* d_in, const int* in_sizes, int n_in,
                              void* d_out, int out_size, void* d_ws, size_t ws_size,
                              hipStream_t stream) {
    const float* x   = (const float*)d_in[0];
    const float* adj = (const float*)d_in[1];
    const float* W1  = (const float*)d_in[2];
    const float* a1s = (const float*)d_in[3];
    const float* a1d = (const float*)d_in[4];
    const float* b1  = (const float*)d_in[5];
    const float* W2  = (const float*)d_in[6];
    const float* a2s = (const float*)d_in[7];
    const float* a2d = (const float*)d_in[8];
    const float* b2  = (const float*)d_in[9];
    float* out = (float*)d_out;

    char* ws = (char*)d_ws;
    float* h1   = (float*)(ws + 0);          // 2,097,152
    float* h2v  = (float*)(ws + 2097152);    // 524,288
    float* als1 = (float*)(ws + 2621440);
    float* ald1 = (float*)(ws + 2654208);
    float* als2 = (float*)(ws + 2686976);
    float* ald2 = (float*)(ws + 2719744);
    int*   gcnt = (int*)  (ws + 2752512);
    int*   gnbr = (int*)  (ws + 2785280);    // 8,388,608

    dim3 blk(256);
    // kB: each block = WPB waves x RPW rows = 16 rows -> 8192/16 = 512 blocks
    kA_h1   <<<dim3(NN / 4), blk, 0, stream>>>(x, W1, a1s, a1d, h1, als1, ald1);
    kB_fused<<<dim3(NN / (WPB * RPW)), blk, 0, stream>>>(
        adj, h1, als1, ald1, b1, W2, a2s, a2d, gcnt, gnbr, h2v, als2, ald2);
    k3_attn2<<<dim3(NN / 4), blk, 0, stream>>>(h2v, als2, ald2, b2, gcnt, gnbr, out);
}

// Round 8
// 77.728 us; speedup vs baseline: 1.5179x; 1.5179x over previous
//
#include <hip/hip_runtime.h>
#include <math.h>

#define NN 8192
#define NEMBD 128
#define NHID 64
#define NCLS 16
#define MAXN 256
#define NEG_SLOPE 0.2f

typedef float f4 __attribute__((ext_vector_type(4)));

__device__ __forceinline__ float wave_max64(float v) {
    v = fmaxf(v, __shfl_xor(v, 1));
    v = fmaxf(v, __shfl_xor(v, 2));
    v = fmaxf(v, __shfl_xor(v, 4));
    v = fmaxf(v, __shfl_xor(v, 8));
    v = fmaxf(v, __shfl_xor(v, 16));
    v = fmaxf(v, __shfl_xor(v, 32));
    return v;
}
__device__ __forceinline__ float wave_sum64(float v) {
    v += __shfl_xor(v, 1);
    v += __shfl_xor(v, 2);
    v += __shfl_xor(v, 4);
    v += __shfl_xor(v, 8);
    v += __shfl_xor(v, 16);
    v += __shfl_xor(v, 32);
    return v;
}

// K1: adj-row scan (software-pipelined, 4KB/wave in flight) with h1 = x@W1
// interleaved. wave per row (2048 blocks -> 32 waves/CU: keeps HBM saturated).
// Sparsity fast path: 53% of 64-value ballot groups are all-zero -> uniform
// scalar branch skips the compaction ops.
__global__ __launch_bounds__(256) void k1_scan_h1(
    const float* __restrict__ adj, const float* __restrict__ x,
    const float* __restrict__ W1,
    const float* __restrict__ a1s, const float* __restrict__ a1d,
    float* __restrict__ h1, float* __restrict__ als, float* __restrict__ ald,
    int* __restrict__ g_cnt, int* __restrict__ g_nbr) {
    __shared__ int s_idx[4][MAXN];
    int wid = threadIdx.x >> 6, lane = threadIdx.x & 63;
    int row = blockIdx.x * 4 + wid;
    const f4* arow = (const f4*)(adj + (size_t)row * NN);
    const float* xr = x + (size_t)row * NEMBD;
    unsigned long long lt = (1ull << lane) - 1ull;
    int base = 0;
    float hacc = 0.f;

    f4 cur0, cur1, cur2, cur3;
    cur0 = __builtin_nontemporal_load(arow + 0 * 64 + lane);
    cur1 = __builtin_nontemporal_load(arow + 1 * 64 + lane);
    cur2 = __builtin_nontemporal_load(arow + 2 * 64 + lane);
    cur3 = __builtin_nontemporal_load(arow + 3 * 64 + lane);

#pragma unroll 1
    for (int c = 0; c < 8; ++c) {
        // h1 interleave: k = c*16 .. c*16+15 (W1 hits L1; x is scalar loads).
        float w1v[16], xv[16];
#pragma unroll
        for (int j = 0; j < 16; ++j) {
            int k = c * 16 + j;
            w1v[j] = W1[k * NHID + lane];
            xv[j] = xr[k];
        }
        // prefetch next chunk (adj, young loads stay in flight)
        f4 nxt0 = {0,0,0,0}, nxt1 = {0,0,0,0}, nxt2 = {0,0,0,0}, nxt3 = {0,0,0,0};
        if (c < 7) {
            const f4* p = arow + (c + 1) * 256 + lane;
            nxt0 = __builtin_nontemporal_load(p + 0 * 64);
            nxt1 = __builtin_nontemporal_load(p + 1 * 64);
            nxt2 = __builtin_nontemporal_load(p + 2 * 64);
            nxt3 = __builtin_nontemporal_load(p + 3 * 64);
        }
#pragma unroll
        for (int j = 0; j < 16; ++j)
            hacc = fmaf(xv[j], w1v[j], hacc);
        // ballots on current chunk (waits only the oldest loads)
#pragma unroll
        for (int j = 0; j < 4; ++j) {
            f4 v = (j == 0) ? cur0 : (j == 1) ? cur1 : (j == 2) ? cur2 : cur3;
            int it = c * 4 + j;
#pragma unroll
            for (int s = 0; s < 4; ++s) {
                bool nz = v[s] > 0.f;
                unsigned long long m = __ballot(nz);
                if (m != 0ull) {           // wave-uniform: 53% of groups skip
                    if (nz) {
                        int pos = base + __popcll(m & lt);
                        s_idx[wid][pos] = it * 256 + lane * 4 + s;
                    }
                    base += __popcll(m);
                }
            }
        }
        cur0 = nxt0; cur1 = nxt1; cur2 = nxt2; cur3 = nxt3;
    }

    int cnt = base < MAXN ? base : MAXN;
    if (lane == 0) g_cnt[row] = cnt;
    for (int n = lane; n < cnt; n += 64)
        g_nbr[(size_t)row * MAXN + n] = s_idx[wid][n];
    h1[(size_t)row * NHID + lane] = hacc;
    float ts = wave_sum64(hacc * a1s[lane]);
    float td = wave_sum64(hacc * a1d[lane]);
    if (lane == 0) { als[row] = ts; ald[row] = td; }
}

// K2: attn-1 softmax + vectorized h1 gather + ELU + h2 = .@W2 + alphas2.
__global__ __launch_bounds__(256) void k2_attn1_h2(
    const float* __restrict__ h1, const float* __restrict__ als,
    const float* __restrict__ ald, const float* __restrict__ b1,
    const float* __restrict__ W2, const float* __restrict__ a2s,
    const float* __restrict__ a2d,
    const int* __restrict__ g_cnt, const int* __restrict__ g_nbr,
    float* __restrict__ h2, float* __restrict__ als2, float* __restrict__ ald2) {
    __shared__ int   s_idx[4][MAXN];
    __shared__ float s_p[4][MAXN];
    __shared__ float s_h[4][NHID];
    int wid = threadIdx.x >> 6, lane = threadIdx.x & 63;
    int row = blockIdx.x * 4 + wid;
    int cnt = g_cnt[row];
    for (int n = lane; n < cnt; n += 64) s_idx[wid][n] = g_nbr[(size_t)row * MAXN + n];

    float asrow = als[row];
    float mloc = -1e30f;
    for (int n = lane; n < cnt; n += 64) {
        float e = asrow + ald[s_idx[wid][n]];
        e = e > 0.f ? e : NEG_SLOPE * e;
        s_p[wid][n] = e;
        mloc = fmaxf(mloc, e);
    }
    float mrow = wave_max64(mloc);
    float ssum = 0.f;
    for (int n = lane; n < cnt; n += 64) {
        float p = __expf(s_p[wid][n] - mrow);
        s_p[wid][n] = p;
        ssum += p;
    }
    float rinv = 1.f / wave_sum64(ssum);

    int c4 = lane & 15, kk = lane >> 4;
    f4 acc = {0.f, 0.f, 0.f, 0.f};
#pragma unroll 8
    for (int n = kk; n < cnt; n += 4) {
        float p = s_p[wid][n];
        f4 v = ((const f4*)(h1 + (size_t)s_idx[wid][n] * NHID))[c4];
        acc.x = fmaf(p, v.x, acc.x);
        acc.y = fmaf(p, v.y, acc.y);
        acc.z = fmaf(p, v.z, acc.z);
        acc.w = fmaf(p, v.w, acc.w);
    }
    acc.x += __shfl_xor(acc.x, 16); acc.y += __shfl_xor(acc.y, 16);
    acc.z += __shfl_xor(acc.z, 16); acc.w += __shfl_xor(acc.w, 16);
    acc.x += __shfl_xor(acc.x, 32); acc.y += __shfl_xor(acc.y, 32);
    acc.z += __shfl_xor(acc.z, 32); acc.w += __shfl_xor(acc.w, 32);
    if (kk == 0) {
        f4 o;
#pragma unroll
        for (int j = 0; j < 4; ++j) {
            float t = acc[j] * rinv + b1[c4 * 4 + j];
            o[j] = t > 0.f ? t : expm1f(t);
        }
        ((f4*)s_h[wid])[c4] = o;
    }
    __builtin_amdgcn_s_barrier();

    int c = lane & 15, k = lane >> 4;
    float a2 = 0.f;
#pragma unroll
    for (int f = k * 16; f < k * 16 + 16; ++f)
        a2 = fmaf(s_h[wid][f], W2[f * NCLS + c], a2);
    a2 += __shfl_xor(a2, 16);
    a2 += __shfl_xor(a2, 32);
    if (lane < 16) h2[(size_t)row * NCLS + lane] = a2;
    float ts = a2 * a2s[c], td = a2 * a2d[c];
    ts += __shfl_xor(ts, 1); td += __shfl_xor(td, 1);
    ts += __shfl_xor(ts, 2); td += __shfl_xor(td, 2);
    ts += __shfl_xor(ts, 4); td += __shfl_xor(td, 4);
    ts += __shfl_xor(ts, 8); td += __shfl_xor(td, 8);
    if (lane == 0) { als2[row] = ts; ald2[row] = td; }
}

// K3: layer-2 GAT. lane = (c4 in 0..3, kk in 0..15).
__global__ __launch_bounds__(256) void k3_attn2(
    const float* __restrict__ h2, const float* __restrict__ als2,
    const float* __restrict__ ald2, const float* __restrict__ b2,
    const int* __restrict__ g_cnt, const int* __restrict__ g_nbr,
    float* __restrict__ out) {
    __shared__ int   s_idx[4][MAXN];
    __shared__ float s_p[4][MAXN];
    int wid = threadIdx.x >> 6, lane = threadIdx.x & 63;
    int row = blockIdx.x * 4 + wid;
    int cnt = g_cnt[row];
    for (int n = lane; n < cnt; n += 64) s_idx[wid][n] = g_nbr[(size_t)row * MAXN + n];

    float asrow = als2[row];
    float mloc = -1e30f;
    for (int n = lane; n < cnt; n += 64) {
        float e = asrow + ald2[s_idx[wid][n]];
        e = e > 0.f ? e : NEG_SLOPE * e;
        s_p[wid][n] = e;
        mloc = fmaxf(mloc, e);
    }
    float mrow = wave_max64(mloc);
    float ssum = 0.f;
    for (int n = lane; n < cnt; n += 64) {
        float p = __expf(s_p[wid][n] - mrow);
        s_p[wid][n] = p;
        ssum += p;
    }
    float rinv = 1.f / wave_sum64(ssum);

    int c4 = lane & 3, kk = lane >> 2;
    f4 acc = {0.f, 0.f, 0.f, 0.f};
#pragma unroll 4
    for (int n = kk; n < cnt; n += 16) {
        float p = s_p[wid][n];
        f4 v = ((const f4*)(h2 + (size_t)s_idx[wid][n] * NCLS))[c4];
        acc.x = fmaf(p, v.x, acc.x);
        acc.y = fmaf(p, v.y, acc.y);
        acc.z = fmaf(p, v.z, acc.z);
        acc.w = fmaf(p, v.w, acc.w);
    }
#pragma unroll
    for (int d = 4; d <= 32; d <<= 1) {
        acc.x += __shfl_xor(acc.x, d); acc.y += __shfl_xor(acc.y, d);
        acc.z += __shfl_xor(acc.z, d); acc.w += __shfl_xor(acc.w, d);
    }
    if (kk == 0) {
        f4 o;
#pragma unroll
        for (int j = 0; j < 4; ++j) {
            float t = acc[j] * rinv + b2[c4 * 4 + j];
            o[j] = t > 0.f ? t : expm1f(t);
        }
        ((f4*)(out + (size_t)row * NCLS))[c4] = o;
    }
}

extern "C" void kernel_launch(void* const* d_in, const int* in_sizes, int n_in,
                              void* d_out, int out_size, void* d_ws, size_t ws_size,
                              hipStream_t stream) {
    const float* x   = (const float*)d_in[0];
    const float* adj = (const float*)d_in[1];
    const float* W1  = (const float*)d_in[2];
    const float* a1s = (const float*)d_in[3];
    const float* a1d = (const float*)d_in[4];
    const float* b1  = (const float*)d_in[5];
    const float* W2  = (const float*)d_in[6];
    const float* a2s = (const float*)d_in[7];
    const float* a2d = (const float*)d_in[8];
    const float* b2  = (const float*)d_in[9];
    float* out = (float*)d_out;

    char* ws = (char*)d_ws;
    float* h1   = (float*)(ws + 0);          // 2,097,152
    float* h2v  = (float*)(ws + 2097152);    // 524,288
    float* als1 = (float*)(ws + 2621440);
    float* ald1 = (float*)(ws + 2654208);
    float* als2 = (float*)(ws + 2686976);
    float* ald2 = (float*)(ws + 2719744);
    int*   gcnt = (int*)  (ws + 2752512);
    int*   gnbr = (int*)  (ws + 2785280);    // 8,388,608

    dim3 blk(256);
    dim3 grid(NN / 4);
    k1_scan_h1 <<<grid, blk, 0, stream>>>(adj, x, W1, a1s, a1d, h1, als1, ald1, gcnt, gnbr);
    k2_attn1_h2<<<grid, blk, 0, stream>>>(h1, als1, ald1, b1, W2, a2s, a2d, gcnt, gnbr,
                                          h2v, als2, ald2);
    k3_attn2   <<<grid, blk, 0, stream>>>(h2v, als2, ald2, b2, gcnt, gnbr, out);
}

// Round 9
// 73.578 us; speedup vs baseline: 1.6035x; 1.0564x over previous
//
#include <hip/hip_runtime.h>
#include <math.h>

#define NN 8192
#define NEMBD 128
#define NHID 64
#define NCLS 16
#define MAXN 256
#define NEG_SLOPE 0.2f

typedef float f4 __attribute__((ext_vector_type(4)));

__device__ __forceinline__ float wave_max64(float v) {
    v = fmaxf(v, __shfl_xor(v, 1));
    v = fmaxf(v, __shfl_xor(v, 2));
    v = fmaxf(v, __shfl_xor(v, 4));
    v = fmaxf(v, __shfl_xor(v, 8));
    v = fmaxf(v, __shfl_xor(v, 16));
    v = fmaxf(v, __shfl_xor(v, 32));
    return v;
}
__device__ __forceinline__ float wave_sum64(float v) {
    v += __shfl_xor(v, 1);
    v += __shfl_xor(v, 2);
    v += __shfl_xor(v, 4);
    v += __shfl_xor(v, 8);
    v += __shfl_xor(v, 16);
    v += __shfl_xor(v, 32);
    return v;
}

// K1: adj-row scan (software-pipelined, 4KB/wave in flight) with h1 = x@W1
// interleaved. wave per row, 2048 blocks. PLAIN loads (no nontemporal): adj is
// 268MB vs 256MB L3 -> during timed graph replays a large fraction stays
// L3-resident and re-serves above HBM rate. x loads are wave-uniform (SMEM);
// W1 is L1-resident; no register staging arrays (keep VGPR low).
__global__ __launch_bounds__(256) void k1_scan_h1(
    const float* __restrict__ adj, const float* __restrict__ x,
    const float* __restrict__ W1,
    const float* __restrict__ a1s, const float* __restrict__ a1d,
    float* __restrict__ h1, float* __restrict__ als, float* __restrict__ ald,
    int* __restrict__ g_cnt, int* __restrict__ g_nbr) {
    __shared__ int s_idx[4][MAXN];
    int wid = threadIdx.x >> 6, lane = threadIdx.x & 63;
    int row = blockIdx.x * 4 + wid;
    const f4* arow = (const f4*)(adj + (size_t)row * NN);
    const float* xr = x + (size_t)row * NEMBD;
    unsigned long long lt = (1ull << lane) - 1ull;
    int base = 0;
    float hacc = 0.f;

    f4 cur0 = arow[0 * 64 + lane];
    f4 cur1 = arow[1 * 64 + lane];
    f4 cur2 = arow[2 * 64 + lane];
    f4 cur3 = arow[3 * 64 + lane];

#pragma unroll 1
    for (int c = 0; c < 8; ++c) {
        // prefetch next chunk (young loads, stay in flight)
        f4 nxt0 = {0,0,0,0}, nxt1 = {0,0,0,0}, nxt2 = {0,0,0,0}, nxt3 = {0,0,0,0};
        if (c < 7) {
            const f4* p = arow + (c + 1) * 256 + lane;
            nxt0 = p[0 * 64];
            nxt1 = p[1 * 64];
            nxt2 = p[2 * 64];
            nxt3 = p[3 * 64];
        }
        // h1 interleave: k = c*16 .. c*16+15 (x: SMEM scalar; W1: L1 vector)
#pragma unroll
        for (int j = 0; j < 16; ++j) {
            int k = c * 16 + j;
            hacc = fmaf(xr[k], W1[k * NHID + lane], hacc);
        }
        // ballots on current chunk (waits only the oldest loads)
#pragma unroll
        for (int j = 0; j < 4; ++j) {
            f4 v = (j == 0) ? cur0 : (j == 1) ? cur1 : (j == 2) ? cur2 : cur3;
            int it = c * 4 + j;
#pragma unroll
            for (int s = 0; s < 4; ++s) {
                bool nz = v[s] > 0.f;
                unsigned long long m = __ballot(nz);
                if (m != 0ull) {           // wave-uniform: ~53% of groups skip
                    if (nz) {
                        int pos = base + __popcll(m & lt);
                        s_idx[wid][pos] = it * 256 + lane * 4 + s;
                    }
                    base += __popcll(m);
                }
            }
        }
        cur0 = nxt0; cur1 = nxt1; cur2 = nxt2; cur3 = nxt3;
    }

    int cnt = base < MAXN ? base : MAXN;
    if (lane == 0) g_cnt[row] = cnt;
    for (int n = lane; n < cnt; n += 64)
        g_nbr[(size_t)row * MAXN + n] = s_idx[wid][n];
    h1[(size_t)row * NHID + lane] = hacc;
    float ts = wave_sum64(hacc * a1s[lane]);
    float td = wave_sum64(hacc * a1d[lane]);
    if (lane == 0) { als[row] = ts; ald[row] = td; }
}

// K2: attn-1 softmax + 8-deep batched h1 gather + ELU + h2 = .@W2 + alphas2.
// Gather: lane = (c4 in 0..15 = f4 chunk, kk in 0..3 = neighbor sublane);
// explicit load-8-then-consume batches keep 8 f4 loads in flight per lane.
__global__ __launch_bounds__(256) void k2_attn1_h2(
    const float* __restrict__ h1, const float* __restrict__ als,
    const float* __restrict__ ald, const float* __restrict__ b1,
    const float* __restrict__ W2, const float* __restrict__ a2s,
    const float* __restrict__ a2d,
    const int* __restrict__ g_cnt, const int* __restrict__ g_nbr,
    float* __restrict__ h2, float* __restrict__ als2, float* __restrict__ ald2) {
    __shared__ int   s_idx[4][MAXN];
    __shared__ float s_p[4][MAXN];
    __shared__ float s_h[4][NHID];
    int wid = threadIdx.x >> 6, lane = threadIdx.x & 63;
    int row = blockIdx.x * 4 + wid;
    int cnt = g_cnt[row];
    for (int n = lane; n < cnt; n += 64) s_idx[wid][n] = g_nbr[(size_t)row * MAXN + n];

    float asrow = als[row];
    float mloc = -1e30f;
    for (int n = lane; n < cnt; n += 64) {
        float e = asrow + ald[s_idx[wid][n]];
        e = e > 0.f ? e : NEG_SLOPE * e;
        s_p[wid][n] = e;
        mloc = fmaxf(mloc, e);
    }
    float mrow = wave_max64(mloc);
    float ssum = 0.f;
    for (int n = lane; n < cnt; n += 64) {
        float p = __expf(s_p[wid][n] - mrow);
        s_p[wid][n] = p;
        ssum += p;
    }
    float rinv = 1.f / wave_sum64(ssum);

    int c4 = lane & 15, kk = lane >> 4;
    f4 acc = {0.f, 0.f, 0.f, 0.f};
    int n = kk;
    // full batches: 8 loads in flight before first consume
    for (; n + 28 < cnt; n += 32) {
        f4 vb0, vb1, vb2, vb3, vb4, vb5, vb6, vb7;
        float pb0, pb1, pb2, pb3, pb4, pb5, pb6, pb7;
        pb0 = s_p[wid][n +  0]; vb0 = ((const f4*)(h1 + (size_t)s_idx[wid][n +  0] * NHID))[c4];
        pb1 = s_p[wid][n +  4]; vb1 = ((const f4*)(h1 + (size_t)s_idx[wid][n +  4] * NHID))[c4];
        pb2 = s_p[wid][n +  8]; vb2 = ((const f4*)(h1 + (size_t)s_idx[wid][n +  8] * NHID))[c4];
        pb3 = s_p[wid][n + 12]; vb3 = ((const f4*)(h1 + (size_t)s_idx[wid][n + 12] * NHID))[c4];
        pb4 = s_p[wid][n + 16]; vb4 = ((const f4*)(h1 + (size_t)s_idx[wid][n + 16] * NHID))[c4];
        pb5 = s_p[wid][n + 20]; vb5 = ((const f4*)(h1 + (size_t)s_idx[wid][n + 20] * NHID))[c4];
        pb6 = s_p[wid][n + 24]; vb6 = ((const f4*)(h1 + (size_t)s_idx[wid][n + 24] * NHID))[c4];
        pb7 = s_p[wid][n + 28]; vb7 = ((const f4*)(h1 + (size_t)s_idx[wid][n + 28] * NHID))[c4];
#pragma unroll
        for (int u = 0; u < 4; ++u) {
            acc[u] = fmaf(pb0, vb0[u], acc[u]); acc[u] = fmaf(pb1, vb1[u], acc[u]);
            acc[u] = fmaf(pb2, vb2[u], acc[u]); acc[u] = fmaf(pb3, vb3[u], acc[u]);
            acc[u] = fmaf(pb4, vb4[u], acc[u]); acc[u] = fmaf(pb5, vb5[u], acc[u]);
            acc[u] = fmaf(pb6, vb6[u], acc[u]); acc[u] = fmaf(pb7, vb7[u], acc[u]);
        }
    }
    for (; n < cnt; n += 4) {
        float p = s_p[wid][n];
        f4 v = ((const f4*)(h1 + (size_t)s_idx[wid][n] * NHID))[c4];
        acc.x = fmaf(p, v.x, acc.x);
        acc.y = fmaf(p, v.y, acc.y);
        acc.z = fmaf(p, v.z, acc.z);
        acc.w = fmaf(p, v.w, acc.w);
    }
    acc.x += __shfl_xor(acc.x, 16); acc.y += __shfl_xor(acc.y, 16);
    acc.z += __shfl_xor(acc.z, 16); acc.w += __shfl_xor(acc.w, 16);
    acc.x += __shfl_xor(acc.x, 32); acc.y += __shfl_xor(acc.y, 32);
    acc.z += __shfl_xor(acc.z, 32); acc.w += __shfl_xor(acc.w, 32);
    if (kk == 0) {
        f4 o;
#pragma unroll
        for (int j = 0; j < 4; ++j) {
            float t = acc[j] * rinv + b1[c4 * 4 + j];
            o[j] = t > 0.f ? t : expm1f(t);
        }
        ((f4*)s_h[wid])[c4] = o;
    }
    __builtin_amdgcn_s_barrier();

    int c = lane & 15, k = lane >> 4;
    float a2 = 0.f;
#pragma unroll
    for (int f = k * 16; f < k * 16 + 16; ++f)
        a2 = fmaf(s_h[wid][f], W2[f * NCLS + c], a2);
    a2 += __shfl_xor(a2, 16);
    a2 += __shfl_xor(a2, 32);
    if (lane < 16) h2[(size_t)row * NCLS + lane] = a2;
    float ts = a2 * a2s[c], td = a2 * a2d[c];
    ts += __shfl_xor(ts, 1); td += __shfl_xor(td, 1);
    ts += __shfl_xor(ts, 2); td += __shfl_xor(td, 2);
    ts += __shfl_xor(ts, 4); td += __shfl_xor(td, 4);
    ts += __shfl_xor(ts, 8); td += __shfl_xor(td, 8);
    if (lane == 0) { als2[row] = ts; ald2[row] = td; }
}

// K3: layer-2 GAT. lane = (c4 in 0..3, kk in 0..15) -> 16 rows in flight.
__global__ __launch_bounds__(256) void k3_attn2(
    const float* __restrict__ h2, const float* __restrict__ als2,
    const float* __restrict__ ald2, const float* __restrict__ b2,
    const int* __restrict__ g_cnt, const int* __restrict__ g_nbr,
    float* __restrict__ out) {
    __shared__ int   s_idx[4][MAXN];
    __shared__ float s_p[4][MAXN];
    int wid = threadIdx.x >> 6, lane = threadIdx.x & 63;
    int row = blockIdx.x * 4 + wid;
    int cnt = g_cnt[row];
    for (int n = lane; n < cnt; n += 64) s_idx[wid][n] = g_nbr[(size_t)row * MAXN + n];

    float asrow = als2[row];
    float mloc = -1e30f;
    for (int n = lane; n < cnt; n += 64) {
        float e = asrow + ald2[s_idx[wid][n]];
        e = e > 0.f ? e : NEG_SLOPE * e;
        s_p[wid][n] = e;
        mloc = fmaxf(mloc, e);
    }
    float mrow = wave_max64(mloc);
    float ssum = 0.f;
    for (int n = lane; n < cnt; n += 64) {
        float p = __expf(s_p[wid][n] - mrow);
        s_p[wid][n] = p;
        ssum += p;
    }
    float rinv = 1.f / wave_sum64(ssum);

    int c4 = lane & 3, kk = lane >> 2;
    f4 acc = {0.f, 0.f, 0.f, 0.f};
#pragma unroll 4
    for (int n = kk; n < cnt; n += 16) {
        float p = s_p[wid][n];
        f4 v = ((const f4*)(h2 + (size_t)s_idx[wid][n] * NCLS))[c4];
        acc.x = fmaf(p, v.x, acc.x);
        acc.y = fmaf(p, v.y, acc.y);
        acc.z = fmaf(p, v.z, acc.z);
        acc.w = fmaf(p, v.w, acc.w);
    }
#pragma unroll
    for (int d = 4; d <= 32; d <<= 1) {
        acc.x += __shfl_xor(acc.x, d); acc.y += __shfl_xor(acc.y, d);
        acc.z += __shfl_xor(acc.z, d); acc.w += __shfl_xor(acc.w, d);
    }
    if (kk == 0) {
        f4 o;
#pragma unroll
        for (int j = 0; j < 4; ++j) {
            float t = acc[j] * rinv + b2[c4 * 4 + j];
            o[j] = t > 0.f ? t : expm1f(t);
        }
        ((f4*)(out + (size_t)row * NCLS))[c4] = o;
    }
}

extern "C" void kernel_launch(void* const* d_in, const int* in_sizes, int n_in,
                              void* d_out, int out_size, void* d_ws, size_t ws_size,
                              hipStream_t stream) {
    const float* x   = (const float*)d_in[0];
    const float* adj = (const float*)d_in[1];
    const float* W1  = (const float*)d_in[2];
    const float* a1s = (const float*)d_in[3];
    const float* a1d = (const float*)d_in[4];
    const float* b1  = (const float*)d_in[5];
    const float* W2  = (const float*)d_in[6];
    const float* a2s = (const float*)d_in[7];
    const float* a2d = (const float*)d_in[8];
    const float* b2  = (const float*)d_in[9];
    float* out = (float*)d_out;

    char* ws = (char*)d_ws;
    float* h1   = (float*)(ws + 0);          // 2,097,152
    float* h2v  = (float*)(ws + 2097152);    // 524,288
    float* als1 = (float*)(ws + 2621440);
    float* ald1 = (float*)(ws + 2654208);
    float* als2 = (float*)(ws + 2686976);
    float* ald2 = (float*)(ws + 2719744);
    int*   gcnt = (int*)  (ws + 2752512);
    int*   gnbr = (int*)  (ws + 2785280);    // 8,388,608

    dim3 blk(256);
    dim3 grid(NN / 4);
    k1_scan_h1 <<<grid, blk, 0, stream>>>(adj, x, W1, a1s, a1d, h1, als1, ald1, gcnt, gnbr);
    k2_attn1_h2<<<grid, blk, 0, stream>>>(h1, als1, ald1, b1, W2, a2s, a2d, gcnt, gnbr,
                                          h2v, als2, ald2);
    k3_attn2   <<<grid, blk, 0, stream>>>(h2v, als2, ald2, b2, gcnt, gnbr, out);
}